// Round 5
// baseline (375.762 us; speedup 1.0000x reference)
//
#include <hip/hip_runtime.h>
#include <math.h>

#define KK 17
#define TT 512
#define DD 1024
#define NBATCH 64
#define NEGC -10000.0f
#define NINF -1e30f
#define EMS 516   // EMT row stride (floats)
#define WTS 520   // Wt row stride (floats): %4==0 (b128 align), banks spread

__device__ __forceinline__ float wsum64(float v) {
#pragma unroll
  for (int s = 32; s >= 1; s >>= 1) v += __shfl_xor(v, s);
  return v;
}
__device__ __forceinline__ int wsum64i(int v) {
#pragma unroll
  for (int s = 32; s >= 1; s >>= 1) v += __shfl_xor(v, s);
  return v;
}
// readlane: VGPR lane -> SGPR broadcast; no LDS on the chain
__device__ __forceinline__ float rl(float x, int i) {
  return __int_as_float(__builtin_amdgcn_readlane(__float_as_int(x), i));
}
// wave64 sum via DPP (no LDS traffic); full sum lands in lane 63.
// update_dpp(old=0,...): excluded/OOB lanes contribute 0 -> sum-safe.
__device__ __forceinline__ float dppsum(float v) {
  float t;
  t = __int_as_float(__builtin_amdgcn_update_dpp(0, __float_as_int(v), 0x111, 0xf, 0xf, true));  v += t; // row_shr:1
  t = __int_as_float(__builtin_amdgcn_update_dpp(0, __float_as_int(v), 0x112, 0xf, 0xf, true));  v += t; // row_shr:2
  t = __int_as_float(__builtin_amdgcn_update_dpp(0, __float_as_int(v), 0x114, 0xf, 0xf, true));  v += t; // row_shr:4
  t = __int_as_float(__builtin_amdgcn_update_dpp(0, __float_as_int(v), 0x118, 0xf, 0xf, true));  v += t; // row_shr:8
  t = __int_as_float(__builtin_amdgcn_update_dpp(0, __float_as_int(v), 0x142, 0xa, 0xf, false)); v += t; // row_bcast:15
  t = __int_as_float(__builtin_amdgcn_update_dpp(0, __float_as_int(v), 0x143, 0xc, 0xf, false)); v += t; // row_bcast:31
  return v;
}
#define MAX3(d, a, b, c) \
  asm("v_max3_f32 %0, %1, %2, %3" : "=v"(d) : "v"(a), "v"(b), "v"(c));

// ---------------- Kernel 1: logits = X @ W + b ----------------
// 512 threads/block, 4 rows/wave, W transposed in LDS -> ds_read_b128,
// float4 X loads, DPP reduce (no LDS reduce traffic).
__global__ __launch_bounds__(512) void k_logits(const float* __restrict__ X,
                                                const float* __restrict__ W,
                                                const float* __restrict__ b,
                                                float* __restrict__ logits,
                                                float* __restrict__ lossp) {
  __shared__ __align__(16) float Wt[KK * WTS];  // 35360 B
  const int tid = threadIdx.x;
  const int lane = tid & 63;
  const int wv = tid >> 6;
  if (blockIdx.x == 0 && tid == 0) *lossp = 0.f;  // replaces memset dispatch
  const long r0 = (long)blockIdx.x * 32 + wv * 4;
  const float* x0 = X + r0 * DD;
  float a0[KK], a1[KK], a2[KK], a3[KK];
#pragma unroll
  for (int j = 0; j < KK; ++j) { a0[j] = 0.f; a1[j] = 0.f; a2[j] = 0.f; a3[j] = 0.f; }

  for (int half = 0; half < 2; ++half) {
    __syncthreads();  // protect previous half before restage
    {
      const float* wr = W + (size_t)(half * 512 + tid) * KK;  // thread owns k=tid
#pragma unroll
      for (int j = 0; j < KK; ++j) Wt[j * WTS + tid] = wr[j];
    }
    __syncthreads();
#pragma unroll
    for (int it = 0; it < 2; ++it) {
      const int k4 = it * 256 + lane * 4;
      const float* xp = x0 + half * 512 + k4;
      float4 xa = *reinterpret_cast<const float4*>(xp);
      float4 xb = *reinterpret_cast<const float4*>(xp + DD);
      float4 xc = *reinterpret_cast<const float4*>(xp + 2 * DD);
      float4 xd = *reinterpret_cast<const float4*>(xp + 3 * DD);
#pragma unroll
      for (int j = 0; j < KK; ++j) {
        float4 w = *reinterpret_cast<const float4*>(&Wt[j * WTS + k4]);
        a0[j] = fmaf(xa.x, w.x, a0[j]); a0[j] = fmaf(xa.y, w.y, a0[j]);
        a0[j] = fmaf(xa.z, w.z, a0[j]); a0[j] = fmaf(xa.w, w.w, a0[j]);
        a1[j] = fmaf(xb.x, w.x, a1[j]); a1[j] = fmaf(xb.y, w.y, a1[j]);
        a1[j] = fmaf(xb.z, w.z, a1[j]); a1[j] = fmaf(xb.w, w.w, a1[j]);
        a2[j] = fmaf(xc.x, w.x, a2[j]); a2[j] = fmaf(xc.y, w.y, a2[j]);
        a2[j] = fmaf(xc.z, w.z, a2[j]); a2[j] = fmaf(xc.w, w.w, a2[j]);
        a3[j] = fmaf(xd.x, w.x, a3[j]); a3[j] = fmaf(xd.y, w.y, a3[j]);
        a3[j] = fmaf(xd.z, w.z, a3[j]); a3[j] = fmaf(xd.w, w.w, a3[j]);
      }
    }
  }
#pragma unroll
  for (int j = 0; j < KK; ++j) {
    a0[j] = dppsum(a0[j]); a1[j] = dppsum(a1[j]);
    a2[j] = dppsum(a2[j]); a3[j] = dppsum(a3[j]);
  }
  // sums live in lane 63; broadcast via readlane, select per output lane
  float v0 = 0.f, v1 = 0.f, v2 = 0.f, v3 = 0.f;
#pragma unroll
  for (int j = 0; j < KK; ++j) {
    float s0 = rl(a0[j], 63), s1 = rl(a1[j], 63), s2 = rl(a2[j], 63), s3 = rl(a3[j], 63);
    if (lane == j) { v0 = s0; v1 = s1; v2 = s2; v3 = s3; }
  }
  if (lane < KK) {
    float bb = b[lane];
    logits[r0 * KK + lane] = v0 + bb;
    logits[(r0 + 1) * KK + lane] = v1 + bb;
    logits[(r0 + 2) * KK + lane] = v2 + bb;
    logits[(r0 + 3) * KK + lane] = v3 + bb;
  }
}

// ---------------- Kernel 2: merged scans ----------------
// 64 blocks (one per batch) x 256 threads.
// wave0 = constrained viterbi, wave1 = scaled forward (logZ), wave2 = gold score.
__global__ __launch_bounds__(256) void k_scan(
    const float* __restrict__ logits, const void* __restrict__ maskp,
    const int* __restrict__ gold, const float* __restrict__ trans,
    const float* __restrict__ st, const float* __restrict__ et,
    const float* __restrict__ ta, const float* __restrict__ sa,
    const float* __restrict__ ea, float* __restrict__ lossp,
    float* __restrict__ predp) {
  __shared__ __align__(16) float EMT[KK * EMS];  // transposed emissions
  __shared__ __align__(4) unsigned char Mk[512];
  __shared__ unsigned char BPt[511 * KK];
  __shared__ unsigned char G2t[256 * KK];
  __shared__ unsigned char G4t[128 * KK];
  __shared__ unsigned char G8t[64 * KK];
  __shared__ unsigned char PR[512];
  __shared__ float red[2];
  __shared__ int shlt;

  const int tid = threadIdx.x;
  const int lane = tid & 63;
  const int wv = tid >> 6;
  const int batch = blockIdx.x;
  const float* Lg = logits + (size_t)batch * TT * KK;

  // mask dtype detect: lengths>=128 so token 1 is masked-in. byte-bool -> byte1==1;
  // int32 -> byte1==0. Never OOB either way.
  const unsigned char* mb = (const unsigned char*)maskp;
  const bool m_is_i32 = (mb[1] == 0);

  // ---- stage emissions transposed + mask ----
  {
    const float4* Lg4 = reinterpret_cast<const float4*>(Lg);
    for (int i = tid; i < (TT * KK) / 4; i += 256) {
      float4 v = Lg4[i];
      int n = i * 4;
      int t0 = n / KK, j0 = n - t0 * KK;
      float vv[4] = {v.x, v.y, v.z, v.w};
#pragma unroll
      for (int e = 0; e < 4; ++e) {
        int j = j0 + e, t = t0;
        if (j >= KK) { j -= KK; t += 1; }
        EMT[j * EMS + t] = vv[e];
      }
    }
    if (m_is_i32) {
      const int* mi = (const int*)maskp + batch * TT;
      for (int t2 = tid; t2 < TT; t2 += 256) Mk[t2] = (unsigned char)(mi[t2] != 0);
    } else {
      const unsigned char* mB = mb + batch * TT;
      for (int t2 = tid; t2 < TT; t2 += 256) Mk[t2] = (unsigned char)(mB[t2] != 0);
    }
  }
  __syncthreads();
  // ---- len (mask is a contiguous prefix of ones) ----
  int len;
  {
    const unsigned int* Mku = reinterpret_cast<const unsigned int*>(Mk);
    unsigned int a = Mku[lane], b2 = Mku[64 + lane];
    int c = (int)(((a * 0x01010101u) >> 24) + ((b2 * 0x01010101u) >> 24));
    len = wsum64i(c);
  }

  const int jc = lane < KK ? lane : (KK - 1);
  const float* EMTrow = EMT + jc * EMS;

  if (wv == 0) {
    // ---------- constrained viterbi ----------
    // value-max: 8x v_max3 (exact; bv is bit-equal to one candidate)
    // backpointer: descending equality scan (first-max, off the v-chain)
    float ctv[KK];
#pragma unroll
    for (int i = 0; i < KK; ++i)
      ctv[i] = (ta[i * KK + jc] > 0.5f) ? trans[i * KK + jc] : NEGC;
    unsigned char* bpw = BPt + jc;
    const bool act = lane < KK;
    float4 A = *reinterpret_cast<const float4*>(EMTrow);  // em[0..3]
    float v = ((sa[jc] > 0.5f) ? st[jc] : NEGC) + A.x;
    int t = 1;

#define VSTEP(EMV)                                                        \
    {                                                                     \
      float c0 = rl(v, 0) + ctv[0], c1 = rl(v, 1) + ctv[1];               \
      float c2 = rl(v, 2) + ctv[2], c3 = rl(v, 3) + ctv[3];               \
      float c4 = rl(v, 4) + ctv[4], c5 = rl(v, 5) + ctv[5];               \
      float c6 = rl(v, 6) + ctv[6], c7 = rl(v, 7) + ctv[7];               \
      float c8 = rl(v, 8) + ctv[8], c9 = rl(v, 9) + ctv[9];               \
      float c10 = rl(v, 10) + ctv[10], c11 = rl(v, 11) + ctv[11];         \
      float c12 = rl(v, 12) + ctv[12], c13 = rl(v, 13) + ctv[13];         \
      float c14 = rl(v, 14) + ctv[14], c15 = rl(v, 15) + ctv[15];         \
      float c16 = rl(v, 16) + ctv[16];                                    \
      float x0, x1, x2, x3, x4, y0, y1, bv;                               \
      MAX3(x0, c0, c1, c2)   MAX3(x1, c3, c4, c5)                         \
      MAX3(x2, c6, c7, c8)   MAX3(x3, c9, c10, c11)                       \
      MAX3(x4, c12, c13, c14)                                             \
      MAX3(y0, x0, x1, x2)   MAX3(y1, x3, x4, c15)                        \
      MAX3(bv, y0, y1, c16)                                               \
      float vn = bv + (EMV);                                              \
      v = (t < len) ? vn : v;                                             \
      int bi = 16;                                                        \
      bi = (c15 == bv) ? 15 : bi; bi = (c14 == bv) ? 14 : bi;             \
      bi = (c13 == bv) ? 13 : bi; bi = (c12 == bv) ? 12 : bi;             \
      bi = (c11 == bv) ? 11 : bi; bi = (c10 == bv) ? 10 : bi;             \
      bi = (c9 == bv) ? 9 : bi;   bi = (c8 == bv) ? 8 : bi;               \
      bi = (c7 == bv) ? 7 : bi;   bi = (c6 == bv) ? 6 : bi;               \
      bi = (c5 == bv) ? 5 : bi;   bi = (c4 == bv) ? 4 : bi;               \
      bi = (c3 == bv) ? 3 : bi;   bi = (c2 == bv) ? 2 : bi;               \
      bi = (c1 == bv) ? 1 : bi;   bi = (c0 == bv) ? 0 : bi;               \
      if (act) bpw[0] = (unsigned char)bi;                                \
      bpw += KK;                                                          \
      ++t;                                                                \
    }

    for (int g = 0; g < 127; ++g) {
      float4 B = *reinterpret_cast<const float4*>(EMTrow + 4 * g + 4);
      VSTEP(A.y) VSTEP(A.z) VSTEP(A.w) VSTEP(B.x)
      A = B;
    }
    VSTEP(A.y) VSTEP(A.z) VSTEP(A.w)  // t = 509,510,511
#undef VSTEP

    // final argmax over lanes 0..16 (first-max)
    float fv = v + ((ea[jc] > 0.5f) ? et[jc] : NEGC);
    float best = rl(fv, 0);
    int bidx = 0;
#pragma unroll
    for (int i = 1; i < KK; ++i) {
      float fi = rl(fv, i);
      bool tk = fi > best;
      best = tk ? fi : best;
      bidx = tk ? i : bidx;
    }
    if (tid == 0) shlt = bidx;
  } else if (wv == 1) {
    // ---------- scaled forward (prob domain); fixed 511 steps, exact freeze ----------
    float Pcol[KK];
#pragma unroll
    for (int i = 0; i < KK; ++i) Pcol[i] = __expf(trans[i * KK + jc]);
    float4 A = *reinterpret_cast<const float4*>(EMTrow);  // em[0..3]
    float a0v = st[jc] + A.x;
    float m0 = rl(a0v, 0);
#pragma unroll
    for (int i = 1; i < KK; ++i) m0 = fmaxf(m0, rl(a0v, i));
    float qown = __expf(a0v - m0);
    float C = m0;
    float ee = __expf(A.y);  // exp(em[1])
    int t = 1;

#define FSTEP(EMNEXT, DOREN)                                                   \
    {                                                                          \
      float q0 = rl(qown, 0), q1 = rl(qown, 1), q2 = rl(qown, 2);              \
      float q3 = rl(qown, 3), q4 = rl(qown, 4), q5 = rl(qown, 5);              \
      float q6 = rl(qown, 6), q7 = rl(qown, 7), q8 = rl(qown, 8);              \
      float q9 = rl(qown, 9), q10 = rl(qown, 10), q11 = rl(qown, 11);          \
      float q12 = rl(qown, 12), q13 = rl(qown, 13), q14 = rl(qown, 14);        \
      float q15 = rl(qown, 15), q16 = rl(qown, 16);                            \
      float da = fmaf(q0, Pcol[0], fmaf(q4, Pcol[4], fmaf(q8, Pcol[8],         \
                 fmaf(q12, Pcol[12], q16 * Pcol[16]))));                       \
      float db = fmaf(q1, Pcol[1], fmaf(q5, Pcol[5], fmaf(q9, Pcol[9],         \
                 q13 * Pcol[13])));                                            \
      float dc = fmaf(q2, Pcol[2], fmaf(q6, Pcol[6], fmaf(q10, Pcol[10],       \
                 q14 * Pcol[14])));                                            \
      float dd = fmaf(q3, Pcol[3], fmaf(q7, Pcol[7], fmaf(q11, Pcol[11],       \
                 q15 * Pcol[15])));                                            \
      float qn = ((da + db) + (dc + dd)) * ee;                                 \
      ee = __expf(EMNEXT);                                                     \
      float qs = (t < len) ? qn : qown;                                        \
      if (DOREN) {                                                             \
        float s0 = ((q0 + q1) + (q2 + q3)) + ((q4 + q5) + (q6 + q7));          \
        float s1 = ((q8 + q9) + (q10 + q11)) + ((q12 + q13) + (q14 + q15));    \
        float s = (s0 + s1) + q16;                                             \
        C += __logf(s);                                                        \
        qs *= (1.0f / s);                                                      \
      }                                                                        \
      qown = qs;                                                               \
      ++t;                                                                     \
    }

    for (int g = 0; g < 127; ++g) {
      float4 B = *reinterpret_cast<const float4*>(EMTrow + 4 * g + 4);
      FSTEP(A.z, false) FSTEP(A.w, false) FSTEP(B.x, false)
      FSTEP(B.y, (g & 1))  // renorm when t%8==0
      A = B;
    }
    FSTEP(A.z, false) FSTEP(A.w, false) FSTEP(A.w, false)  // t=509..511
#undef FSTEP

    float term = qown * __expf(et[jc]);
    float S = rl(term, 0);
#pragma unroll
    for (int i = 1; i < KK; ++i) S += rl(term, i);
    if (lane == 0) red[0] = C + __logf(S);  // logZ
  } else if (wv == 2) {
    // ---------- gold path score ----------
    const int* gb = gold + batch * TT;
    float esum = 0.f, tsum = 0.f;
#pragma unroll
    for (int u = 0; u < 8; ++u) {
      int t = lane + 64 * u;
      int gt = gb[t];
      float mt = (float)Mk[t];
      esum += mt * EMT[gt * EMS + t];
      int tn = (t + 1 < TT) ? t + 1 : TT - 1;
      int gn = gb[tn];
      float mtr = (t + 1 < TT && Mk[t + 1]) ? 1.f : 0.f;
      tsum += mtr * trans[gt * KK + gn];
    }
    float ssum = wsum64(esum + tsum);
    if (lane == 0) red[1] = ssum + st[gb[0]] + et[gb[len - 1]];
  }
  __syncthreads();
  if (tid == 0) atomicAdd(lossp, red[0] - red[1]);  // loss = sum(logZ - score)

  const int lt = shlt;
  // ---- compose backpointer maps: g_s(x) = mask[s+1] ? bp[s][x] : x ----
  {
    int m = tid;  // 0..255
    int s1 = 2 * m + 1, s0b = 2 * m;
    bool u1 = (s1 < 511) && Mk[s1 + 1];
    bool u0 = Mk[s0b + 1] != 0;
#pragma unroll
    for (int x = 0; x < KK; ++x) {
      int y = u1 ? (int)BPt[s1 * KK + x] : x;
      int z = u0 ? (int)BPt[s0b * KK + y] : y;
      G2t[m * KK + x] = (unsigned char)z;
    }
  }
  __syncthreads();
  if (tid < 128) {
    int p = tid;
#pragma unroll
    for (int x = 0; x < KK; ++x) {
      int y = G2t[(2 * p + 1) * KK + x];
      G4t[p * KK + x] = G2t[2 * p * KK + y];
    }
  }
  __syncthreads();
  if (tid < 64) {
    int p = tid;
#pragma unroll
    for (int x = 0; x < KK; ++x) {
      int y = G4t[(2 * p + 1) * KK + x];
      G8t[p * KK + x] = G4t[2 * p * KK + y];
    }
  }
  __syncthreads();
  if (tid == 0) {  // serial chain: 64 dependent LDS lookups
    int x = lt;
    for (int p = 63; p >= 0; --p) {
      x = G8t[p * KK + x];
      PR[8 * p] = (unsigned char)x;
    }
  }
  __syncthreads();
  if (tid < 64) {
    int p = tid;
    int src = (p == 63) ? lt : (int)PR[8 * p + 8];
    PR[8 * p + 4] = G4t[(2 * p + 1) * KK + src];
  }
  __syncthreads();
  if (tid < 128) {
    int m = tid;
    int src = (m == 127) ? lt : (int)PR[4 * m + 4];
    PR[4 * m + 2] = G2t[(2 * m + 1) * KK + src];
  }
  __syncthreads();
  {
    int m = tid;  // 0..255
    int s = 2 * m + 1;
    int src = (m == 255) ? lt : (int)PR[2 * m + 2];
    int val = ((s < 511) && Mk[s + 1]) ? (int)BPt[s * KK + src] : src;
    PR[2 * m + 1] = (unsigned char)val;
  }
  __syncthreads();
  float* po = predp + batch * TT;
  for (int t2 = tid; t2 < TT; t2 += 256) po[t2] = Mk[t2] ? (float)PR[t2] : 0.f;
}

extern "C" void kernel_launch(void* const* d_in, const int* in_sizes, int n_in,
                              void* d_out, int out_size, void* d_ws, size_t ws_size,
                              hipStream_t stream) {
  const float* mlm = (const float*)d_in[0];
  const void* mask = d_in[1];
  const int* gold = (const int*)d_in[2];
  const float* W = (const float*)d_in[3];
  const float* b = (const float*)d_in[4];
  const float* trans = (const float*)d_in[5];
  const float* st = (const float*)d_in[6];
  const float* et = (const float*)d_in[7];
  const float* ta = (const float*)d_in[8];
  const float* sa = (const float*)d_in[9];
  const float* ea = (const float*)d_in[10];

  float* out = (float*)d_out;
  float* logits = out;                             // [64*512*17]
  float* lossp = out + (size_t)NBATCH * TT * KK;   // [1]
  float* predp = lossp + 1;                        // [64*512]

  k_logits<<<dim3(1024), dim3(512), 0, stream>>>(mlm, W, b, logits, lossp);
  k_scan<<<dim3(64), dim3(256), 0, stream>>>(logits, mask, gold, trans, st, et,
                                             ta, sa, ea, lossp, predp);
}

// Round 6
// 302.042 us; speedup vs baseline: 1.2441x; 1.2441x over previous
//
#include <hip/hip_runtime.h>
#include <math.h>

#define KK 17
#define TT 512
#define DD 1024
#define NBATCH 64
#define NEGC -10000.0f
#define NINF -1e30f
#define EMS 516   // EMT row stride (floats)
#define WTS 520   // Wt row stride (floats)

__device__ __forceinline__ float wsum64(float v) {
#pragma unroll
  for (int s = 32; s >= 1; s >>= 1) v += __shfl_xor(v, s);
  return v;
}
__device__ __forceinline__ int wsum64i(int v) {
#pragma unroll
  for (int s = 32; s >= 1; s >>= 1) v += __shfl_xor(v, s);
  return v;
}
// readlane: VGPR lane -> SGPR broadcast; no LDS on the chain
__device__ __forceinline__ float rl(float x, int i) {
  return __int_as_float(__builtin_amdgcn_readlane(__float_as_int(x), i));
}
// wave64 sum via DPP; full sum lands in lane 63.
__device__ __forceinline__ float dppsum(float v) {
  float t;
  t = __int_as_float(__builtin_amdgcn_update_dpp(0, __float_as_int(v), 0x111, 0xf, 0xf, true));  v += t;
  t = __int_as_float(__builtin_amdgcn_update_dpp(0, __float_as_int(v), 0x112, 0xf, 0xf, true));  v += t;
  t = __int_as_float(__builtin_amdgcn_update_dpp(0, __float_as_int(v), 0x114, 0xf, 0xf, true));  v += t;
  t = __int_as_float(__builtin_amdgcn_update_dpp(0, __float_as_int(v), 0x118, 0xf, 0xf, true));  v += t;
  t = __int_as_float(__builtin_amdgcn_update_dpp(0, __float_as_int(v), 0x142, 0xa, 0xf, false)); v += t;
  t = __int_as_float(__builtin_amdgcn_update_dpp(0, __float_as_int(v), 0x143, 0xc, 0xf, false)); v += t;
  return v;
}

// ---------------- Kernel 1: logits = X @ W + b (unchanged from R5) ----------------
__global__ __launch_bounds__(512) void k_logits(const float* __restrict__ X,
                                                const float* __restrict__ W,
                                                const float* __restrict__ b,
                                                float* __restrict__ logits,
                                                float* __restrict__ lossp) {
  __shared__ __align__(16) float Wt[KK * WTS];
  const int tid = threadIdx.x;
  const int lane = tid & 63;
  const int wv = tid >> 6;
  if (blockIdx.x == 0 && tid == 0) *lossp = 0.f;
  const long r0 = (long)blockIdx.x * 32 + wv * 4;
  const float* x0 = X + r0 * DD;
  float a0[KK], a1[KK], a2[KK], a3[KK];
#pragma unroll
  for (int j = 0; j < KK; ++j) { a0[j] = 0.f; a1[j] = 0.f; a2[j] = 0.f; a3[j] = 0.f; }

  for (int half = 0; half < 2; ++half) {
    __syncthreads();
    {
      const float* wr = W + (size_t)(half * 512 + tid) * KK;
#pragma unroll
      for (int j = 0; j < KK; ++j) Wt[j * WTS + tid] = wr[j];
    }
    __syncthreads();
#pragma unroll
    for (int it = 0; it < 2; ++it) {
      const int k4 = it * 256 + lane * 4;
      const float* xp = x0 + half * 512 + k4;
      float4 xa = *reinterpret_cast<const float4*>(xp);
      float4 xb = *reinterpret_cast<const float4*>(xp + DD);
      float4 xc = *reinterpret_cast<const float4*>(xp + 2 * DD);
      float4 xd = *reinterpret_cast<const float4*>(xp + 3 * DD);
#pragma unroll
      for (int j = 0; j < KK; ++j) {
        float4 w = *reinterpret_cast<const float4*>(&Wt[j * WTS + k4]);
        a0[j] = fmaf(xa.x, w.x, a0[j]); a0[j] = fmaf(xa.y, w.y, a0[j]);
        a0[j] = fmaf(xa.z, w.z, a0[j]); a0[j] = fmaf(xa.w, w.w, a0[j]);
        a1[j] = fmaf(xb.x, w.x, a1[j]); a1[j] = fmaf(xb.y, w.y, a1[j]);
        a1[j] = fmaf(xb.z, w.z, a1[j]); a1[j] = fmaf(xb.w, w.w, a1[j]);
        a2[j] = fmaf(xc.x, w.x, a2[j]); a2[j] = fmaf(xc.y, w.y, a2[j]);
        a2[j] = fmaf(xc.z, w.z, a2[j]); a2[j] = fmaf(xc.w, w.w, a2[j]);
        a3[j] = fmaf(xd.x, w.x, a3[j]); a3[j] = fmaf(xd.y, w.y, a3[j]);
        a3[j] = fmaf(xd.z, w.z, a3[j]); a3[j] = fmaf(xd.w, w.w, a3[j]);
      }
    }
  }
#pragma unroll
  for (int j = 0; j < KK; ++j) {
    a0[j] = dppsum(a0[j]); a1[j] = dppsum(a1[j]);
    a2[j] = dppsum(a2[j]); a3[j] = dppsum(a3[j]);
  }
  float v0 = 0.f, v1 = 0.f, v2 = 0.f, v3 = 0.f;
#pragma unroll
  for (int j = 0; j < KK; ++j) {
    float s0 = rl(a0[j], 63), s1 = rl(a1[j], 63), s2 = rl(a2[j], 63), s3 = rl(a3[j], 63);
    if (lane == j) { v0 = s0; v1 = s1; v2 = s2; v3 = s3; }
  }
  if (lane < KK) {
    float bb = b[lane];
    logits[r0 * KK + lane] = v0 + bb;
    logits[(r0 + 1) * KK + lane] = v1 + bb;
    logits[(r0 + 2) * KK + lane] = v2 + bb;
    logits[(r0 + 3) * KK + lane] = v3 + bb;
  }
}

// first-max select: strict '>' keeps LEFT (smaller index) on ties == np.argmax
#define ARGM(vl, il, vr, ir, vo, io) \
  { bool tk = (vr) > (vl); vo = tk ? (vr) : (vl); io = tk ? (ir) : (il); }

// ---------------- Kernel 2: merged scans, deferred-bp viterbi ----------------
// 64 blocks x 256 threads. wave0 = viterbi VALUES only (v history -> LDS ring),
// wave1 = scaled forward, wave2 = gold (interval 0) then recon, wave3 = recon.
// Backpointers reconstructed in parallel from the ring, one interval behind.
__global__ __launch_bounds__(256) void k_scan(
    const float* __restrict__ logits, const void* __restrict__ maskp,
    const int* __restrict__ gold, const float* __restrict__ trans,
    const float* __restrict__ st, const float* __restrict__ et,
    const float* __restrict__ ta, const float* __restrict__ sa,
    const float* __restrict__ ea, float* __restrict__ lossp,
    float* __restrict__ predp) {
  __shared__ __align__(16) float EMT[KK * EMS];   // transposed emissions [j][t]
  __shared__ __align__(4) unsigned char Mk[512];
  __shared__ float VH[128 * KK];                  // v-history ring (slot = t & 127)
  __shared__ float CTL[KK * KK];                  // constrained transitions ct[i][j]
  __shared__ unsigned char BPt[511 * KK];
  __shared__ unsigned char G2t[256 * KK];
  __shared__ unsigned char G4t[128 * KK];
  __shared__ unsigned char G8t[64 * KK];
  __shared__ unsigned char PR[512];
  __shared__ float red[2];
  __shared__ int shlt;

  const int tid = threadIdx.x;
  const int lane = tid & 63;
  const int wv = tid >> 6;
  const int batch = blockIdx.x;
  const float* Lg = logits + (size_t)batch * TT * KK;

  // mask dtype detect (lengths>=128 so token 1 is masked-in)
  const unsigned char* mb = (const unsigned char*)maskp;
  const bool m_is_i32 = (mb[1] == 0);

  // ---- stage: emissions transposed, mask, constrained transitions ----
  {
    const float4* Lg4 = reinterpret_cast<const float4*>(Lg);
    for (int i = tid; i < (TT * KK) / 4; i += 256) {
      float4 v = Lg4[i];
      int n = i * 4;
      int t0 = n / KK, j0 = n - t0 * KK;
      float vv[4] = {v.x, v.y, v.z, v.w};
#pragma unroll
      for (int e = 0; e < 4; ++e) {
        int j = j0 + e, t = t0;
        if (j >= KK) { j -= KK; t += 1; }
        EMT[j * EMS + t] = vv[e];
      }
    }
    if (m_is_i32) {
      const int* mi = (const int*)maskp + batch * TT;
      for (int t2 = tid; t2 < TT; t2 += 256) Mk[t2] = (unsigned char)(mi[t2] != 0);
    } else {
      const unsigned char* mB = mb + batch * TT;
      for (int t2 = tid; t2 < TT; t2 += 256) Mk[t2] = (unsigned char)(mB[t2] != 0);
    }
    for (int i = tid; i < KK * KK; i += 256)
      CTL[i] = (ta[i] > 0.5f) ? trans[i] : NEGC;
  }
  __syncthreads();
  // ---- len (mask is a contiguous prefix of ones) ----
  int len;
  {
    const unsigned int* Mku = reinterpret_cast<const unsigned int*>(Mk);
    unsigned int a = Mku[lane], b2 = Mku[64 + lane];
    int c = (int)(((a * 0x01010101u) >> 24) + ((b2 * 0x01010101u) >> 24));
    len = wsum64i(c);
  }

  const int jc = lane < KK ? lane : (KK - 1);
  const float* EMTrow = EMT + jc * EMS;

  // ---- per-wave scan state ----
  float v = 0.f;                    // viterbi value (wave0)
  float ctv[KK];                    // wave0
  float Pcol[KK];                   // wave1
  float qown = 0.f, C = 0.f, ee = 0.f;  // wave1
  int t = 1;                        // global step for waves 0,1

  if (wv == 0) {
#pragma unroll
    for (int i = 0; i < KK; ++i) ctv[i] = CTL[i * KK + jc];
    v = ((sa[jc] > 0.5f) ? st[jc] : NEGC) + EMTrow[0];
    VH[jc] = v;                     // ring slot 0 = v after t=0 (lanes>=16 write same value)
  } else if (wv == 1) {
#pragma unroll
    for (int i = 0; i < KK; ++i) Pcol[i] = __expf(trans[i * KK + jc]);
    float a0v = st[jc] + EMTrow[0];
    float m0 = rl(a0v, 0);
#pragma unroll
    for (int i = 1; i < KK; ++i) m0 = fmaxf(m0, rl(a0v, i));
    qown = __expf(a0v - m0);
    C = m0;
    ee = __expf(EMTrow[1]);
  }

#define VSTEP6                                                             \
    {                                                                      \
      float em = EMTrow[t];                                                \
      float c0 = rl(v, 0) + ctv[0], c1 = rl(v, 1) + ctv[1];                \
      float c2 = rl(v, 2) + ctv[2], c3 = rl(v, 3) + ctv[3];                \
      float c4 = rl(v, 4) + ctv[4], c5 = rl(v, 5) + ctv[5];                \
      float c6 = rl(v, 6) + ctv[6], c7 = rl(v, 7) + ctv[7];                \
      float c8 = rl(v, 8) + ctv[8], c9 = rl(v, 9) + ctv[9];                \
      float c10 = rl(v, 10) + ctv[10], c11 = rl(v, 11) + ctv[11];          \
      float c12 = rl(v, 12) + ctv[12], c13 = rl(v, 13) + ctv[13];          \
      float c14 = rl(v, 14) + ctv[14], c15 = rl(v, 15) + ctv[15];          \
      float c16 = rl(v, 16) + ctv[16];                                     \
      float m01 = fmaxf(c0, c1), m23 = fmaxf(c2, c3);                      \
      float m45 = fmaxf(c4, c5), m67 = fmaxf(c6, c7);                      \
      float m89 = fmaxf(c8, c9), mab = fmaxf(c10, c11);                    \
      float mcd = fmaxf(c12, c13), mef = fmaxf(c14, c15);                  \
      float n0 = fmaxf(m01, m23), n1 = fmaxf(m45, m67);                    \
      float n2 = fmaxf(m89, mab), n3 = fmaxf(mcd, mef);                    \
      float p0 = fmaxf(n0, n1), p1 = fmaxf(n2, n3);                        \
      float bv = fmaxf(fmaxf(p0, p1), c16);                                \
      float vn = bv + em;                                                  \
      v = (t < len) ? vn : v;                                              \
      VH[(t & 127) * KK + jc] = v;                                         \
      ++t;                                                                 \
    }

#define FSTEP6(REN)                                                            \
    {                                                                          \
      float en_raw = EMTrow[t + 1];                                            \
      float q0 = rl(qown, 0), q1 = rl(qown, 1), q2 = rl(qown, 2);              \
      float q3 = rl(qown, 3), q4 = rl(qown, 4), q5 = rl(qown, 5);              \
      float q6 = rl(qown, 6), q7 = rl(qown, 7), q8 = rl(qown, 8);              \
      float q9 = rl(qown, 9), q10 = rl(qown, 10), q11 = rl(qown, 11);          \
      float q12 = rl(qown, 12), q13 = rl(qown, 13), q14 = rl(qown, 14);        \
      float q15 = rl(qown, 15), q16 = rl(qown, 16);                            \
      float da = fmaf(q0, Pcol[0], fmaf(q4, Pcol[4], fmaf(q8, Pcol[8],         \
                 fmaf(q12, Pcol[12], q16 * Pcol[16]))));                       \
      float db = fmaf(q1, Pcol[1], fmaf(q5, Pcol[5], fmaf(q9, Pcol[9],         \
                 q13 * Pcol[13])));                                            \
      float dc = fmaf(q2, Pcol[2], fmaf(q6, Pcol[6], fmaf(q10, Pcol[10],       \
                 q14 * Pcol[14])));                                            \
      float dd = fmaf(q3, Pcol[3], fmaf(q7, Pcol[7], fmaf(q11, Pcol[11],       \
                 q15 * Pcol[15])));                                            \
      float qn = ((da + db) + (dc + dd)) * ee;                                 \
      ee = __expf(en_raw);                                                     \
      float qs = (t < len) ? qn : qown;                                        \
      if (REN) {                                                               \
        float s0 = ((q0 + q1) + (q2 + q3)) + ((q4 + q5) + (q6 + q7));          \
        float s1 = ((q8 + q9) + (q10 + q11)) + ((q12 + q13) + (q14 + q15));    \
        float s = (s0 + s1) + q16;                                             \
        C += __logf(s);                                                        \
        qs *= (1.0f / s);                                                      \
      }                                                                        \
      qown = qs;                                                               \
      ++t;                                                                     \
    }

  // 10 intervals: k=0..8 do 56 steps (t=1..504), k=9 does 7 (t=505..511).
  // Recon (waves 2,3) trails scan by one interval; ring window is race-free
  // (producer is at most 112 rows ahead of oldest consumer read, ring=128).
  for (int k = 0; k < 10; ++k) {
    if (wv == 0) {
      if (k < 9) {
#pragma unroll
        for (int s2 = 0; s2 < 56; ++s2) VSTEP6
      } else {
#pragma unroll
        for (int s2 = 0; s2 < 7; ++s2) VSTEP6
      }
    } else if (wv == 1) {
      if (k < 9) {
#pragma unroll
        for (int g = 0; g < 7; ++g) {
          FSTEP6(0) FSTEP6(0) FSTEP6(0) FSTEP6(0)
          FSTEP6(0) FSTEP6(0) FSTEP6(0) FSTEP6(1)   // renorm at t%8==0
        }
      } else {
#pragma unroll
        for (int s2 = 0; s2 < 7; ++s2) FSTEP6(0)
        // finalize logZ
        float term = qown * __expf(et[jc]);
        float S = rl(term, 0);
#pragma unroll
        for (int i = 1; i < KK; ++i) S += rl(term, i);
        if (lane == 0) red[0] = C + __logf(S);
      }
    } else {
      if (k == 0) {
        if (wv == 2) {
          // ---------- gold path score ----------
          const int* gb = gold + batch * TT;
          float esum = 0.f, tsum = 0.f;
#pragma unroll
          for (int u = 0; u < 8; ++u) {
            int tg = lane + 64 * u;
            int gt = gb[tg];
            float mt = (float)Mk[tg];
            esum += mt * EMT[gt * EMS + tg];
            int tn = (tg + 1 < TT) ? tg + 1 : TT - 1;
            int gn = gb[tn];
            float mtr = (tg + 1 < TT && Mk[tg + 1]) ? 1.f : 0.f;
            tsum += mtr * trans[gt * KK + gn];
          }
          float ssum = wsum64(esum + tsum);
          if (lane == 0) red[1] = ssum + st[gb[0]] + et[gb[len - 1]];
        }
      } else {
        // ---------- backpointer reconstruction for interval k-1 ----------
        const int sbase = 56 * (k - 1);
        for (int n = tid - 128; n < 56 * KK; n += 128) {
          int tl = (n * 61681) >> 20;  // n/17 exact for n<2^20
          int j = n - tl * 17;
          int s = sbase + tl;
          const float* vr = &VH[(s & 127) * KK];
          const float* ct = &CTL[j];
          float c0 = vr[0] + ct[0];     float c1 = vr[1] + ct[17];
          float c2 = vr[2] + ct[34];    float c3 = vr[3] + ct[51];
          float c4 = vr[4] + ct[68];    float c5 = vr[5] + ct[85];
          float c6 = vr[6] + ct[102];   float c7 = vr[7] + ct[119];
          float c8 = vr[8] + ct[136];   float c9 = vr[9] + ct[153];
          float c10 = vr[10] + ct[170]; float c11 = vr[11] + ct[187];
          float c12 = vr[12] + ct[204]; float c13 = vr[13] + ct[221];
          float c14 = vr[14] + ct[238]; float c15 = vr[15] + ct[255];
          float c16 = vr[16] + ct[272];
          float d0, d1, d2, d3, d4, d5, d6, d7;
          int j0, j1, j2, j3, j4, j5, j6, j7;
          ARGM(c0, 0, c1, 1, d0, j0)     ARGM(c2, 2, c3, 3, d1, j1)
          ARGM(c4, 4, c5, 5, d2, j2)     ARGM(c6, 6, c7, 7, d3, j3)
          ARGM(c8, 8, c9, 9, d4, j4)     ARGM(c10, 10, c11, 11, d5, j5)
          ARGM(c12, 12, c13, 13, d6, j6) ARGM(c14, 14, c15, 15, d7, j7)
          float e0, e1, e2, e3; int k0, k1, k2, k3;
          ARGM(d0, j0, d1, j1, e0, k0)   ARGM(d2, j2, d3, j3, e1, k1)
          ARGM(d4, j4, d5, j5, e2, k2)   ARGM(d6, j6, d7, j7, e3, k3)
          float f0, f1; int l0, l1;
          ARGM(e0, k0, e1, k1, f0, l0)   ARGM(e2, k2, e3, k3, f1, l1)
          float g0; int m0i;
          ARGM(f0, l0, f1, l1, g0, m0i)
          float bvv; int bi;
          ARGM(g0, m0i, c16, 16, bvv, bi)
          BPt[s * KK + j] = (unsigned char)bi;
        }
      }
    }
    __syncthreads();
  }
#undef VSTEP6
#undef FSTEP6

  // ---- tail: last 7 bp rows (s=504..510) + final viterbi argmax ----
  if (wv == 0) {
    float fv = v + ((ea[jc] > 0.5f) ? et[jc] : NEGC);
    float best = rl(fv, 0);
    int bidx = 0;
#pragma unroll
    for (int i = 1; i < KK; ++i) {
      float fi = rl(fv, i);
      bool tk = fi > best;
      best = tk ? fi : best;
      bidx = tk ? i : bidx;
    }
    if (tid == 0) shlt = bidx;
  } else if (wv >= 2) {
    for (int n = tid - 128; n < 7 * KK; n += 128) {
      int tl = (n * 61681) >> 20;
      int j = n - tl * 17;
      int s = 504 + tl;
      const float* vr = &VH[(s & 127) * KK];
      const float* ct = &CTL[j];
      float c0 = vr[0] + ct[0];     float c1 = vr[1] + ct[17];
      float c2 = vr[2] + ct[34];    float c3 = vr[3] + ct[51];
      float c4 = vr[4] + ct[68];    float c5 = vr[5] + ct[85];
      float c6 = vr[6] + ct[102];   float c7 = vr[7] + ct[119];
      float c8 = vr[8] + ct[136];   float c9 = vr[9] + ct[153];
      float c10 = vr[10] + ct[170]; float c11 = vr[11] + ct[187];
      float c12 = vr[12] + ct[204]; float c13 = vr[13] + ct[221];
      float c14 = vr[14] + ct[238]; float c15 = vr[15] + ct[255];
      float c16 = vr[16] + ct[272];
      float d0, d1, d2, d3, d4, d5, d6, d7;
      int j0, j1, j2, j3, j4, j5, j6, j7;
      ARGM(c0, 0, c1, 1, d0, j0)     ARGM(c2, 2, c3, 3, d1, j1)
      ARGM(c4, 4, c5, 5, d2, j2)     ARGM(c6, 6, c7, 7, d3, j3)
      ARGM(c8, 8, c9, 9, d4, j4)     ARGM(c10, 10, c11, 11, d5, j5)
      ARGM(c12, 12, c13, 13, d6, j6) ARGM(c14, 14, c15, 15, d7, j7)
      float e0, e1, e2, e3; int k0, k1, k2, k3;
      ARGM(d0, j0, d1, j1, e0, k0)   ARGM(d2, j2, d3, j3, e1, k1)
      ARGM(d4, j4, d5, j5, e2, k2)   ARGM(d6, j6, d7, j7, e3, k3)
      float f0, f1; int l0, l1;
      ARGM(e0, k0, e1, k1, f0, l0)   ARGM(e2, k2, e3, k3, f1, l1)
      float g0; int m0i;
      ARGM(f0, l0, f1, l1, g0, m0i)
      float bvv; int bi;
      ARGM(g0, m0i, c16, 16, bvv, bi)
      BPt[s * KK + j] = (unsigned char)bi;
    }
  }
  if (tid == 0) atomicAdd(lossp, red[0] - red[1]);  // loss = sum(logZ - score)
  __syncthreads();

  const int lt = shlt;
  // ---- compose backpointer maps: g_s(x) = mask[s+1] ? bp[s][x] : x ----
  {
    int m = tid;  // 0..255
    int s1 = 2 * m + 1, s0b = 2 * m;
    bool u1 = (s1 < 511) && Mk[s1 + 1];
    bool u0 = Mk[s0b + 1] != 0;
#pragma unroll
    for (int x = 0; x < KK; ++x) {
      int y = u1 ? (int)BPt[s1 * KK + x] : x;
      int z = u0 ? (int)BPt[s0b * KK + y] : y;
      G2t[m * KK + x] = (unsigned char)z;
    }
  }
  __syncthreads();
  if (tid < 128) {
    int p = tid;
#pragma unroll
    for (int x = 0; x < KK; ++x) {
      int y = G2t[(2 * p + 1) * KK + x];
      G4t[p * KK + x] = G2t[2 * p * KK + y];
    }
  }
  __syncthreads();
  if (tid < 64) {
    int p = tid;
#pragma unroll
    for (int x = 0; x < KK; ++x) {
      int y = G4t[(2 * p + 1) * KK + x];
      G8t[p * KK + x] = G4t[2 * p * KK + y];
    }
  }
  __syncthreads();
  if (tid == 0) {  // serial chain: 64 dependent LDS lookups
    int x = lt;
    for (int p = 63; p >= 0; --p) {
      x = G8t[p * KK + x];
      PR[8 * p] = (unsigned char)x;
    }
  }
  __syncthreads();
  if (tid < 64) {
    int p = tid;
    int src = (p == 63) ? lt : (int)PR[8 * p + 8];
    PR[8 * p + 4] = G4t[(2 * p + 1) * KK + src];
  }
  __syncthreads();
  if (tid < 128) {
    int m = tid;
    int src = (m == 127) ? lt : (int)PR[4 * m + 4];
    PR[4 * m + 2] = G2t[(2 * m + 1) * KK + src];
  }
  __syncthreads();
  {
    int m = tid;  // 0..255
    int s = 2 * m + 1;
    int src = (m == 255) ? lt : (int)PR[2 * m + 2];
    int val = ((s < 511) && Mk[s + 1]) ? (int)BPt[s * KK + src] : src;
    PR[2 * m + 1] = (unsigned char)val;
  }
  __syncthreads();
  float* po = predp + batch * TT;
  for (int t2 = tid; t2 < TT; t2 += 256) po[t2] = Mk[t2] ? (float)PR[t2] : 0.f;
}

extern "C" void kernel_launch(void* const* d_in, const int* in_sizes, int n_in,
                              void* d_out, int out_size, void* d_ws, size_t ws_size,
                              hipStream_t stream) {
  const float* mlm = (const float*)d_in[0];
  const void* mask = d_in[1];
  const int* gold = (const int*)d_in[2];
  const float* W = (const float*)d_in[3];
  const float* b = (const float*)d_in[4];
  const float* trans = (const float*)d_in[5];
  const float* st = (const float*)d_in[6];
  const float* et = (const float*)d_in[7];
  const float* ta = (const float*)d_in[8];
  const float* sa = (const float*)d_in[9];
  const float* ea = (const float*)d_in[10];

  float* out = (float*)d_out;
  float* logits = out;                             // [64*512*17]
  float* lossp = out + (size_t)NBATCH * TT * KK;   // [1]
  float* predp = lossp + 1;                        // [64*512]

  k_logits<<<dim3(1024), dim3(512), 0, stream>>>(mlm, W, b, logits, lossp);
  k_scan<<<dim3(64), dim3(256), 0, stream>>>(logits, mask, gold, trans, st, et,
                                             ta, sa, ea, lossp, predp);
}